// Round 18
// baseline (617.144 us; speedup 1.0000x reference)
//
#include <hip/hip_runtime.h>
#include <hip/hip_bf16.h>
#include <math.h>

#define HW 9216
#define IMG 96

typedef __bf16 bf16x8 __attribute__((ext_vector_type(8)));
typedef float  f32x4  __attribute__((ext_vector_type(4)));

__device__ __forceinline__ void gload16(const void* g, void* l) {
    __builtin_amdgcn_global_load_lds((const unsigned int*)g, (unsigned int*)l, 16, 0, 0);
}

#define WAITVN(N) asm volatile("s_waitcnt vmcnt(" #N ")" ::: "memory")
#define BARX()    { asm volatile("" ::: "memory"); __builtin_amdgcn_s_barrier(); asm volatile("" ::: "memory"); }

// ---------------------------------------------------------------------------
// BOTH NCHW fp32 -> NHWC bf16 transposes in one launch.
// grid (144, 20, 8): by<16 -> x (512ch, stride 512); by>=16 -> y2 (128ch).
// ---------------------------------------------------------------------------
__global__ __launch_bounds__(256) void nchw2nhwc2_kernel(
    const float* __restrict__ xsrc, const float* __restrict__ y2src,
    __hip_bfloat16* __restrict__ xdst, __hip_bfloat16* __restrict__ y2dst)
{
    __shared__ float tile[32][65];
    const int px0 = blockIdx.x * 64;
    const int by  = blockIdx.y;
    const int n   = blockIdx.z;
    const float* src; __hip_bfloat16* dst; long nss; int dstride, c0;
    if (by < 16) { src = xsrc;  dst = xdst;  nss = 512L * HW; dstride = 512; c0 = by * 32; }
    else         { src = y2src; dst = y2dst; nss = 256L * HW; dstride = 128; c0 = (by - 16) * 32; }
    const int tid = threadIdx.x;
    const int tx = tid & 63, ty = tid >> 6;
    #pragma unroll
    for (int i = 0; i < 8; ++i)
        tile[ty + i * 4][tx] = src[n * nss + (long)(c0 + ty + i * 4) * HW + px0 + tx];
    __syncthreads();
    const int ci = tid & 31, pxl = tid >> 5;
    #pragma unroll
    for (int j = 0; j < 8; ++j) {
        int px = pxl + j * 8;
        dst[((long)n * HW + px0 + px) * dstride + c0 + ci] = __float2bfloat16(tile[ci][px]);
    }
}

// ---------------------------------------------------------------------------
// all four weight conversions in ONE launch: dst[t][co][ci] = bf16(src[co][ci][t])
// ---------------------------------------------------------------------------
__global__ __launch_bounds__(256) void wconv_all_kernel(
    const float* __restrict__ w_down, const float* __restrict__ w_ks1,
    const float* __restrict__ w_fb,   const float* __restrict__ w_fuse,
    __hip_bfloat16* __restrict__ d_down, __hip_bfloat16* __restrict__ d_ks1,
    __hip_bfloat16* __restrict__ d_fb,   __hip_bfloat16* __restrict__ d_fuse)
{
    const float* src; __hip_bfloat16* dst; int cout, cin, taps;
    switch (blockIdx.y) {
        case 0:  src = w_down; dst = d_down; cout = 256; cin = 512; taps = 1; break;
        case 1:  src = w_ks1;  dst = d_ks1;  cout = 128; cin = 128; taps = 9; break;
        case 2:  src = w_fb;   dst = d_fb;   cout = 256; cin = 256; taps = 9; break;
        default: src = w_fuse; dst = d_fuse; cout = 256; cin = 512; taps = 9; break;
    }
    int idx = blockIdx.x * 256 + threadIdx.x;
    if (idx >= cout * cin) return;
    int co = idx / cin, ci = idx % cin;
    for (int t = 0; t < taps; ++t)
        dst[((long)t * cout + co) * cin + ci] = __float2bfloat16(src[(long)idx * taps + t]);
}

// ---------------------------------------------------------------------------
// MFMA implicit-GEMM conv (TAPS=9: 3x3 pad=1; TAPS=1: 1x1), bf16 in, fp32 acc.
// R10 geometry + R17 B-address folding. R18: staging pointer advance is an
// UNCONDITIONAL add of a precomputed per-pointer step (stepN = valid?64:0),
// with a wave-uniform scalar branch to stageX (stepX = valid?dAB:0) at the
// SPLIT crossing — removes the per-chunk cndmask chains.
// Counted per-wave vmcnt (per-wave MIN issued). T1 XCD swizzle.
// NCHW output only for co >= nchw_co0.
// ---------------------------------------------------------------------------
template<int CIN, int TAPS, bool SPLIT, int NYL2>
__global__ __launch_bounds__(512, 1) void mfma_conv(
    const __hip_bfloat16* __restrict__ in_a,
    const __hip_bfloat16* __restrict__ in_b,
    const __hip_bfloat16* __restrict__ w_t,
    const float* __restrict__ bias,
    float* __restrict__ out_nchw, long nchw_nstride, int nchw_co0,
    __hip_bfloat16* __restrict__ out_nhwc, int nhwc_stride,
    int cout,
    const float* __restrict__ bng, const float* __restrict__ bnb,
    const float* __restrict__ pra,
    const __hip_bfloat16* __restrict__ zeropage)
{
    constexpr int ROWS = (TAPS == 9) ? 10 : 8;      // staged rows
    constexpr int COLS = (TAPS == 9) ? 98 : 96;
    constexpr int HOFF = (TAPS == 9) ? 1 : 0;
    constexpr int PSTR = SPLIT ? 256 : CIN;
    constexpr int NSEG_IN = ROWS * COLS * 4;        // 3920 / 3072
    constexpr int NSEG_W  = TAPS * 32 * 4;          // 1152 / 128
    constexpr int IN_BYTES = NSEG_IN * 16;          // 62720 / 49152
    constexpr int BUF = IN_BYTES + NSEG_W * 16;     // 81152 / 51200
    constexpr int NCHUNK = CIN / 32;
    constexpr int FULL_IN = NSEG_IN / 512;          // 7 / 6
    constexpr int IN_TAIL = NSEG_IN % 512;          // 336 / 0
    constexpr int FULL_W  = NSEG_W / 512;           // 2 / 0
    constexpr int W_TAIL  = NSEG_W % 512;           // 128 / 128
    constexpr int IT_IN = FULL_IN + (IN_TAIL ? 1 : 0);
    constexpr int IT_W  = FULL_W + (W_TAIL ? 1 : 0);
    constexpr int GROUPS = (TAPS == 9) ? 3 : 1;
    constexpr int KXN    = (TAPS == 9) ? 3 : 1;

    extern __shared__ __align__(16) char lds[];     // 2*BUF

    // ---- XCD-aware decode of flat block id ----
    const int id  = blockIdx.x;
    const int yb  = (id >> 3) & ((1 << NYL2) - 1);
    const int xz  = (id & 7) + 8 * (id >> (3 + NYL2));
    const int h0  = (xz % 12) * 8;
    const int n   = xz / 12;
    const int cob = yb * 32;

    const int tid  = threadIdx.x;
    const int lane = tid & 63;
    const int wave = tid >> 6;
    const int l16  = lane & 15, lg = lane >> 4;

    const long dAB = SPLIT ? ((const char*)in_b - (const char*)in_a - 448) : 0;

    // ---- input staging pointers + precomputed steps ----
    const char* inptr[IT_IN];
    long stepN[IT_IN];
    long stepX[IT_IN];
    #pragma unroll
    for (int t = 0; t < IT_IN; ++t) {
        int seg = tid + t * 512;
        int s2 = (seg < NSEG_IN) ? seg : 0;
        int pix = s2 >> 2, qp = s2 & 3;
        int r = pix / COLS, c = pix % COLS;
        int h = h0 + r - HOFF, w = c - HOFF;
        int q = qp ^ ((c >> 1) & 3);                 // inverse-swizzled source slot
        bool valid = (h >= 0 && h < IMG && w >= 0 && w < IMG);
        inptr[t] = valid
            ? (const char*)(in_a + ((long)n * HW + h * IMG + w) * PSTR + q * 8)
            : (const char*)zeropage;
        stepN[t] = valid ? 64 : 0;
        stepX[t] = valid ? dAB : 0;
    }
    // ---- weight staging pointers ----
    const char* wptr[IT_W];
    #pragma unroll
    for (int t = 0; t < IT_W; ++t) {
        int seg = tid + t * 512;
        int s2 = (seg < NSEG_W) ? seg : 0;
        int tap = s2 >> 7, rem = s2 & 127;
        int co = rem >> 2, qp = rem & 3;
        int q = qp ^ ((co >> 1) & 3);
        wptr[t] = (const char*)(w_t + ((long)tap * cout + cob + co) * CIN + q * 8);
    }

    auto stage_w = [&](char* wb) {
        #pragma unroll
        for (int t = 0; t < FULL_W; ++t) {
            gload16(wptr[t], wb + (tid + t * 512) * 16);
            wptr[t] += 64;
        }
        if (W_TAIL) {
            if (tid < W_TAIL) {
                gload16(wptr[IT_W - 1], wb + (tid + FULL_W * 512) * 16);
                wptr[IT_W - 1] += 64;
            }
        }
    };
    auto stageN = [&](int bb) {
        char* ib = lds + bb * BUF;
        #pragma unroll
        for (int t = 0; t < FULL_IN; ++t) {
            gload16(inptr[t], ib + (tid + t * 512) * 16);
            inptr[t] += stepN[t];
        }
        if (IN_TAIL) {
            if (tid < IN_TAIL) {
                gload16(inptr[IT_IN - 1], ib + (tid + FULL_IN * 512) * 16);
                inptr[IT_IN - 1] += stepN[IT_IN - 1];
            }
        }
        stage_w(ib + IN_BYTES);
    };
    auto stageX = [&](int bb) {
        char* ib = lds + bb * BUF;
        #pragma unroll
        for (int t = 0; t < FULL_IN; ++t) {
            gload16(inptr[t], ib + (tid + t * 512) * 16);
            inptr[t] += stepX[t];
        }
        if (IN_TAIL) {
            if (tid < IN_TAIL) {
                gload16(inptr[IT_IN - 1], ib + (tid + FULL_IN * 512) * 16);
                inptr[IT_IN - 1] += stepX[IT_IN - 1];
            }
        }
        stage_w(ib + IN_BYTES);
    };

    f32x4 acc[2][6];
    #pragma unroll
    for (int m = 0; m < 2; ++m)
        #pragma unroll
        for (int nf = 0; nf < 6; ++nf) acc[m][nf] = (f32x4){0.f, 0.f, 0.f, 0.f};

    const int qa = lg ^ ((l16 >> 1) & 3);
    const int a_off = l16 * 64 + qa * 16;

    stageN(0);
    WAITVN(0); BARX();

    for (int ch = 0; ch < NCHUNK; ++ch) {
        if (ch + 1 < NCHUNK) {
            if (SPLIT && (ch + 1) == 7) { if constexpr (SPLIT) stageX((ch + 1) & 1); }
            else                        { stageN((ch + 1) & 1); }
            // per-wave MIN of loads just issued (conservative)
            if constexpr (TAPS == 9) {
                if (wave < 2) { WAITVN(11); } else if (wave < 5) { WAITVN(10); } else { WAITVN(9); }
            } else {
                if (wave < 2) { WAITVN(7); } else { WAITVN(6); }
            }
        } else {
            WAITVN(0);
        }
        BARX();

        const char* ib = lds + (ch & 1) * BUF;
        const char* wb = ib + IN_BYTES;
        __builtin_amdgcn_s_setprio(1);
        #pragma unroll
        for (int g = 0; g < GROUPS; ++g) {
            const char* rowb = ib + (wave + g) * (COLS * 64);
            #pragma unroll
            for (int kx = 0; kx < KXN; ++kx) {
                const int tap = g * 3 + kx;          // compile-time in unroll
                bf16x8 a0 = *(const bf16x8*)(wb + tap * 2048 + a_off);
                bf16x8 a1 = *(const bf16x8*)(wb + tap * 2048 + 1024 + a_off);
                const int c0 = l16 + kx;
                const int qb = lg ^ ((c0 >> 1) & 3); // invariant in nf
                const char* bbase = rowb + c0 * 64 + qb * 16;
                #pragma unroll
                for (int nf = 0; nf < 6; ++nf) {
                    bf16x8 b = *(const bf16x8*)(bbase + nf * 1024);
                    acc[0][nf] = __builtin_amdgcn_mfma_f32_16x16x32_bf16(a0, b, acc[0][nf], 0, 0, 0);
                    acc[1][nf] = __builtin_amdgcn_mfma_f32_16x16x32_bf16(a1, b, acc[1][nf], 0, 0, 0);
                }
            }
        }
        __builtin_amdgcn_s_setprio(0);
        BARX();
    }

    // ---- epilogue ----
    const int hrow = h0 + wave;
    #pragma unroll
    for (int m = 0; m < 2; ++m) {
        const int co = cob + m * 16 + lg * 4;
        float bs[4], g4[4], b4[4], p4[4];
        #pragma unroll
        for (int r = 0; r < 4; ++r) bs[r] = bias ? bias[co + r] : 0.f;
        if (bng) {
            #pragma unroll
            for (int r = 0; r < 4; ++r) { g4[r] = bng[co + r]; b4[r] = bnb[co + r]; p4[r] = pra[co + r]; }
        }
        #pragma unroll
        for (int nf = 0; nf < 6; ++nf) {
            const int wcol = nf * 16 + l16;
            const long px = (long)hrow * IMG + wcol;
            float v[4];
            #pragma unroll
            for (int r = 0; r < 4; ++r) {
                v[r] = acc[m][nf][r] + bs[r];
                if (bng) {
                    v[r] = v[r] * g4[r] + b4[r];
                    v[r] = (v[r] >= 0.f) ? v[r] : p4[r] * v[r];
                }
            }
            if (out_nchw && co >= nchw_co0) {
                #pragma unroll
                for (int r = 0; r < 4; ++r)
                    out_nchw[(long)n * nchw_nstride + (long)(co - nchw_co0 + r) * HW + px] = v[r];
            }
            if (out_nhwc) {
                union { __hip_bfloat16 h[4]; uint2 u; } pk;
                #pragma unroll
                for (int r = 0; r < 4; ++r) pk.h[r] = __float2bfloat16(v[r]);
                *reinterpret_cast<uint2*>(&out_nhwc[((long)n * HW + px) * nhwc_stride + co]) = pk.u;
            }
        }
    }
}

// ---------------------------------------------------------------------------
// BOTH pools in one launch. grid (137, 8): bx<9 -> x-pool bin bx (from cat_x
// NHWC ch0..127); bx>=9 -> y-pool channel bx-9 (fp32 NCHW).
// ---------------------------------------------------------------------------
__global__ __launch_bounds__(256) void pool_both_kernel(
    const __hip_bfloat16* __restrict__ catx, const float* __restrict__ y,
    float* __restrict__ gl, float* __restrict__ py)
{
    const int bx = blockIdx.x;
    const int n  = blockIdx.y;
    const int tid = threadIdx.x;
    __shared__ float red[16][16][8];
    if (bx < 9) {
        const int bin = bx;
        const int bh = bin / 3, bw = bin % 3;
        const int cg  = tid & 15;
        const int pxl = tid >> 4;
        const long pbase = (long)n * HW;
        float acc[8];
        #pragma unroll
        for (int j = 0; j < 8; ++j) acc[j] = 0.f;
        for (int it = 0; it < 64; ++it) {
            const int i = pxl + it * 16;
            const int h = bh * 32 + (i >> 5);
            const int w = bw * 32 + (i & 31);
            bf16x8 v = *reinterpret_cast<const bf16x8*>(&catx[(pbase + h * IMG + w) * 256 + cg * 8]);
            #pragma unroll
            for (int j = 0; j < 8; ++j) acc[j] += (float)v[j];
        }
        #pragma unroll
        for (int j = 0; j < 8; ++j) red[pxl][cg][j] = acc[j];
        __syncthreads();
        if (tid < 128) {
            const int cg2 = tid & 15, j = tid >> 4;
            float s = 0.f;
            #pragma unroll
            for (int p = 0; p < 16; ++p) s += red[p][cg2][j];
            gl[((long)n * 128 + cg2 * 8 + j) * 9 + bin] = s * (1.f / 1024.f);
        }
    } else {
        const int c = bx - 9;
        const float* src = y + ((long)n * 256 + c) * HW;
        float local[9];
        #pragma unroll
        for (int k = 0; k < 9; ++k) local[k] = 0.f;
        for (int i = tid; i < HW; i += 256) {
            int h = i / 96, w = i % 96;
            local[(h / 32) * 3 + (w / 32)] += src[i];
        }
        float* red2 = &red[0][0][0];   // reuse LDS: [9][4]
        const int wv = tid >> 6, lane = tid & 63;
        #pragma unroll
        for (int k = 0; k < 9; ++k) {
            float v = local[k];
            for (int off = 32; off > 0; off >>= 1) v += __shfl_down(v, off, 64);
            if (lane == 0) red2[k * 4 + wv] = v;
        }
        __syncthreads();
        if (tid < 9) {
            float s = (red2[tid * 4 + 0] + red2[tid * 4 + 1] + red2[tid * 4 + 2] + red2[tid * 4 + 3]) * (1.f / 1024.f);
            py[((long)n * 128 + c) * 9 + tid] = s;
        }
    }
}

// ---------------------------------------------------------------------------
__global__ __launch_bounds__(128) void attkc_kernel(
    const float* __restrict__ gl, const float* __restrict__ py,
    const float* __restrict__ w_ce, const float* __restrict__ w_gd,
    const float* __restrict__ bng, const float* __restrict__ bnb,
    const float* __restrict__ w_kc, const float* __restrict__ b_kc,
    float* __restrict__ kc)
{
    const int n = blockIdx.x, c = threadIdx.x;
    __shared__ float py_s[128][9];
    #pragma unroll
    for (int k = 0; k < 9; ++k) py_s[c][k] = py[((long)n * 128 + c) * 9 + k];
    __syncthreads();
    float g[9];
    #pragma unroll
    for (int k = 0; k < 9; ++k) g[k] = gl[((long)n * 128 + c) * 9 + k];
    float t[5];
    #pragma unroll
    for (int l = 0; l < 5; ++l) {
        float s = 0.f;
        #pragma unroll
        for (int k = 0; k < 9; ++k) s += g[k] * w_ce[l * 9 + k];
        s = s * bng[c] + bnb[c];
        t[l] = s > 0.f ? s : 0.f;
    }
    float att[9];
    #pragma unroll
    for (int k = 0; k < 9; ++k) {
        float s = 0.f;
        #pragma unroll
        for (int l = 0; l < 5; ++l) s += t[l] * w_gd[k * 5 + l];
        att[k] = 1.f / (1.f + expf(-s));
    }
    float kc0[9];
    float bk = b_kc[c];
    #pragma unroll
    for (int k = 0; k < 9; ++k) kc0[k] = bk;
    for (int c2 = 0; c2 < 128; ++c2) {
        float wv = w_kc[c * 128 + c2];
        #pragma unroll
        for (int k = 0; k < 9; ++k) kc0[k] += wv * py_s[c2][k];
    }
    #pragma unroll
    for (int k = 0; k < 9; ++k)
        kc[((long)n * 128 + c) * 9 + k] = kc0[k] * att[k];
}

// ---------------------------------------------------------------------------
// ks = 1x1 conv 128->9 on ksmid_bf [N][HW][128] bf16 (NHWC)
// ---------------------------------------------------------------------------
__global__ __launch_bounds__(256) void ks_nhwc_kernel(
    const __hip_bfloat16* __restrict__ ksmid, const float* __restrict__ w_ks2,
    const float* __restrict__ b_ks2, float* __restrict__ ks)
{
    __shared__ float w_s[9 * 128];
    const int tid = threadIdx.x;
    for (int i = tid; i < 1152; i += 256) w_s[i] = w_ks2[i];
    __syncthreads();
    const int p = blockIdx.x * 256 + tid;
    const int n = blockIdx.y;
    const __hip_bfloat16* row = ksmid + ((long)n * HW + p) * 128;
    float acc[9];
    #pragma unroll
    for (int k = 0; k < 9; ++k) acc[k] = b_ks2[k];
    #pragma unroll
    for (int vq = 0; vq < 16; ++vq) {
        bf16x8 v = *reinterpret_cast<const bf16x8*>(&row[vq * 8]);
        #pragma unroll
        for (int j = 0; j < 8; ++j) {
            float f = (float)v[j];
            #pragma unroll
            for (int k = 0; k < 9; ++k) acc[k] += w_s[k * 128 + vq * 8 + j] * f;
        }
    }
    #pragma unroll
    for (int k = 0; k < 9; ++k) ks[((long)n * 9 + k) * HW + p] = acc[k];
}

// ---------------------------------------------------------------------------
// ksp = conv3x3(x2, w_sp1, pad=1) -> 1 channel, NHWC data-parallel.
// ---------------------------------------------------------------------------
__global__ __launch_bounds__(256) void ksp_nhwc_kernel(
    const __hip_bfloat16* __restrict__ catx, const float* __restrict__ w_sp1,
    float* __restrict__ ksp)
{
    __shared__ float w_s[9][128];
    const int tid = threadIdx.x;
    for (int i = tid; i < 1152; i += 256) {
        int ci = i / 9, tap = i % 9;            // src layout [ci][tap]
        w_s[tap][ci] = w_sp1[i];
    }
    __syncthreads();
    const int p = blockIdx.x * 256 + tid;
    const int n = blockIdx.y;
    const int h = p / 96, w = p % 96;
    const long pbase = (long)n * HW;
    float acc = 0.f;
    #pragma unroll
    for (int ky = 0; ky < 3; ++ky) {
        const int hh = h + ky - 1;
        if (hh < 0 || hh >= IMG) continue;
        #pragma unroll
        for (int kx = 0; kx < 3; ++kx) {
            const int ww = w + kx - 1;
            if (ww < 0 || ww >= IMG) continue;
            const int tap = ky * 3 + kx;
            const __hip_bfloat16* row = &catx[(pbase + hh * IMG + ww) * 256 + 128];
            #pragma unroll
            for (int vq = 0; vq < 16; ++vq) {
                bf16x8 v = *reinterpret_cast<const bf16x8*>(&row[vq * 8]);
                #pragma unroll
                for (int j = 0; j < 8; ++j)
                    acc += w_s[tap][vq * 8 + j] * (float)v[j];
            }
        }
    }
    ksp[pbase + p] = acc;
}

// ---------------------------------------------------------------------------
__global__ __launch_bounds__(256) void sp_kernel(
    const float* __restrict__ ksp, const float* __restrict__ w_sp,
    float* __restrict__ sp)
{
    const int p = blockIdx.x * 256 + threadIdx.x;
    const int n = blockIdx.y;
    const int h = p / 96, w = p % 96;
    const float* kp = ksp + (long)n * HW;
    float acc = 0.f;
    #pragma unroll
    for (int dy = 0; dy < 3; ++dy)
        #pragma unroll
        for (int dx = 0; dx < 3; ++dx) {
            int hh = h + dy - 1, ww = w + dx - 1;
            if (hh < 0 || hh >= 96 || ww < 0 || ww >= 96) continue;
            float s = 0.f, m = -1e30f;
            #pragma unroll
            for (int iy = 0; iy < 3; ++iy)
                #pragma unroll
                for (int ix = 0; ix < 3; ++ix) {
                    int h2 = hh + iy - 1, w2 = ww + ix - 1;
                    float v = (h2 >= 0 && h2 < 96 && w2 >= 0 && w2 < 96) ? kp[h2 * 96 + w2] : 0.f;
                    s += v; m = fmaxf(m, v);
                }
            acc += w_sp[dy * 3 + dx] * (s * (1.f / 9.f)) + w_sp[9 + dy * 3 + dx] * m;
        }
    sp[(long)n * HW + p] = 1.f / (1.f + expf(-acc));
}

// ---------------------------------------------------------------------------
// spatial_after + channel_after in one launch. grid (224, 8):
// bx<96 -> channel row h=bx (catfb ch0..127); bx>=96 -> spatial cc=bx-96
// (catfb ch128..255, raw-reshape gather cc = p/72). xd = x2 only.
// ---------------------------------------------------------------------------
__global__ __launch_bounds__(256) void spatchan_kernel(
    const float* __restrict__ xd, const float* __restrict__ ks,
    const float* __restrict__ sp, const __hip_bfloat16* __restrict__ catx,
    const float* __restrict__ kc, __hip_bfloat16* __restrict__ catfb)
{
    const int bx = blockIdx.x;
    const int n  = blockIdx.y;
    const int tid = threadIdx.x;
    __shared__ float plane[HW];
    if (bx < 96) {
        // ---- channel_after ----
        const int h  = bx;
        const int cg = (tid & 15) * 8;
        const int w0 = tid >> 4;
        float k9[8][9];
        #pragma unroll
        for (int j = 0; j < 8; ++j)
            #pragma unroll
            for (int t = 0; t < 9; ++t) k9[j][t] = kc[((long)n * 128 + cg + j) * 9 + t];
        const long pbase = (long)n * HW;
        for (int it = 0; it < 6; ++it) {
            const int w = w0 + it * 16;
            float acc[8];
            #pragma unroll
            for (int j = 0; j < 8; ++j) acc[j] = 0.f;
            #pragma unroll
            for (int ky = 0; ky < 3; ++ky) {
                const int hh = h + ky - 1;
                if (hh < 0 || hh >= IMG) continue;
                #pragma unroll
                for (int kx = 0; kx < 3; ++kx) {
                    const int ww = w + kx - 1;
                    if (ww < 0 || ww >= IMG) continue;
                    bf16x8 v = *reinterpret_cast<const bf16x8*>(
                        &catx[(pbase + hh * IMG + ww) * 256 + cg]);
                    #pragma unroll
                    for (int j = 0; j < 8; ++j)
                        acc[j] += k9[j][ky * 3 + kx] * (float)v[j];
                }
            }
            union { __hip_bfloat16 hh[8]; uint4 u; } pk;
            #pragma unroll
            for (int j = 0; j < 8; ++j) pk.hh[j] = __float2bfloat16(acc[j]);
            *reinterpret_cast<uint4*>(&catfb[(pbase + h * IMG + w) * 256 + cg]) = pk.u;
        }
    } else {
        // ---- spatial_after ----
        const int cc = bx - 96;
        const float* src = xd + ((long)n * 128 + cc) * HW;
        for (int i = tid; i < HW / 4; i += 256)
            *reinterpret_cast<float4*>(&plane[i * 4]) = *reinterpret_cast<const float4*>(&src[i * 4]);
        __syncthreads();
        const int c  = tid & 127;
        const int pr = tid >> 7;
        const int c9 = c * 9;
        for (int j = 0; j < 36; ++j) {
            const int pl = pr + j * 2;
            const int p  = cc * 72 + pl;
            float spv = sp[(long)n * HW + p];
            float kv[9];
            #pragma unroll
            for (int k = 0; k < 9; ++k) kv[k] = ks[((long)n * 9 + k) * HW + p] * spv;
            const int base = pl * 1152 + c9;
            int kk0 = base / 9216;
            int r20 = base - kk0 * 9216;
            int h20 = r20 / 96;
            int w20 = r20 - h20 * 96;
            float acc = 0.f;
            #pragma unroll
            for (int k = 0; k < 9; ++k) {
                int kk = kk0, h2 = h20, w2 = w20 + k;
                if (w2 >= 96) { h2 += 1; w2 -= 96; }
                if (h2 >= 96) { kk += 1; h2 -= 96; }
                int hh = h2 + kk / 3 - 1;
                int ww = w2 + kk % 3 - 1;
                float v = (hh >= 0 && hh < 96 && ww >= 0 && ww < 96) ? plane[hh * 96 + ww] : 0.f;
                acc += v * kv[k];
            }
            catfb[((long)n * HW + p) * 256 + 128 + c] = __float2bfloat16(acc);
        }
    }
}

// ---------------------------------------------------------------------------
extern "C" void kernel_launch(void* const* d_in, const int* in_sizes, int n_in,
                              void* d_out, int out_size, void* d_ws, size_t ws_size,
                              hipStream_t stream)
{
    const float* x      = (const float*)d_in[0];
    const float* y      = (const float*)d_in[1];
    const float* w_down = (const float*)d_in[2];
    const float* b_down = (const float*)d_in[3];
    const float* w_ce   = (const float*)d_in[4];
    const float* w_gd   = (const float*)d_in[5];
    const float* bn_g   = (const float*)d_in[6];
    const float* bn_b   = (const float*)d_in[7];
    const float* w_kc   = (const float*)d_in[8];
    const float* b_kc   = (const float*)d_in[9];
    const float* w_ks1  = (const float*)d_in[10];
    const float* b_ks1  = (const float*)d_in[11];
    const float* w_ks2  = (const float*)d_in[12];
    const float* b_ks2  = (const float*)d_in[13];
    const float* w_sp1  = (const float*)d_in[14];
    const float* w_sp   = (const float*)d_in[15];
    const float* w_fb   = (const float*)d_in[16];
    const float* b_fb   = (const float*)d_in[17];
    const float* w_fuse = (const float*)d_in[18];
    const float* bn2_g  = (const float*)d_in[19];
    const float* bn2_b  = (const float*)d_in[20];
    const float* prelu  = (const float*)d_in[21];
    float* out = (float*)d_out;
    char* ws = (char*)d_ws;

    const long HWl = HW;
    // --- workspace layout ---
    float* xd = (float*)ws;                               ws += 8L * 128 * HWl * 4;  // 37.7MB (x2 only)
    char* region2 = ws;                                   ws += 8L * HWl * 512 * 2;  // 75.5MB
    __hip_bfloat16* x_t      = (__hip_bfloat16*)region2;          // [N][HW][512] bf16
    __hip_bfloat16* cat_r1   = (__hip_bfloat16*)region2;          // [N][HW][256] bf16
    __hip_bfloat16* ksmid_bf = (__hip_bfloat16*)region2;          // [N][HW][128] bf16
    __hip_bfloat16* catfb    = (__hip_bfloat16*)(region2 + 8L * HWl * 256 * 2); // [N][HW][256]
    __hip_bfloat16* cat_x  = (__hip_bfloat16*)ws;         ws += 8L * HWl * 256 * 2;  // 37.7MB
    __hip_bfloat16* y2t    = (__hip_bfloat16*)ws;         ws += 8L * HWl * 128 * 2;  // 18.9MB
    __hip_bfloat16* wdown_bf = (__hip_bfloat16*)ws;       ws += 1L * 256 * 512 * 2;
    __hip_bfloat16* wks1_bf  = (__hip_bfloat16*)ws;       ws += 9L * 128 * 128 * 2;
    __hip_bfloat16* wfb_bf   = (__hip_bfloat16*)ws;       ws += 9L * 256 * 256 * 2;
    __hip_bfloat16* wfuse_bf = (__hip_bfloat16*)ws;       ws += 9L * 256 * 512 * 2;
    float* ks   = (float*)ws;  ws += 8L * 9 * HWl * 4;
    float* ksp  = (float*)ws;  ws += 8L * HWl * 4;
    float* spb  = (float*)ws;  ws += 8L * HWl * 4;
    float* gl   = (float*)ws;  ws += 8L * 128 * 9 * 4;
    float* py   = (float*)ws;  ws += 8L * 128 * 9 * 4;
    float* kc   = (float*)ws;  ws += 8L * 128 * 9 * 4;
    __hip_bfloat16* zp = (__hip_bfloat16*)ws;  ws += 256;

    (void)hipMemsetAsync((void*)zp, 0, 256, stream);

    // all weight conversions in one launch
    wconv_all_kernel<<<dim3(512, 4), 256, 0, stream>>>(
        w_down, w_ks1, w_fb, w_fuse, wdown_bf, wks1_bf, wfb_bf, wfuse_bf);

    // x AND y2 -> NHWC bf16 in one launch
    nchw2nhwc2_kernel<<<dim3(144, 20, 8), 256, 0, stream>>>(
        x, y + 128L * HWl, x_t, y2t);

    // 1x1 down conv -> xd (x2 only, fp32) + cat_x (bf16 NHWC)
    mfma_conv<512, 1, false, 3><<<dim3(768), 512, 102400, stream>>>(
        x_t, nullptr, wdown_bf, b_down, xd, 128L * HWl, 128, cat_x, 256, 256,
        nullptr, nullptr, nullptr, zp);

    // pools (both) / attention
    pool_both_kernel<<<dim3(137, 8), 256, 0, stream>>>(cat_x, y, gl, py);
    attkc_kernel<<<dim3(8), 128, 0, stream>>>(gl, py, w_ce, w_gd, bn_g, bn_b, w_kc, b_kc, kc);

    // ks_mid = conv3x3(y2) -> ksmid_bf (bf16 NHWC; x_t dead now)
    mfma_conv<128, 9, false, 2><<<dim3(384), 512, 162304, stream>>>(
        y2t, nullptr, wks1_bf, b_ks1, nullptr, 0, 0, ksmid_bf, 128, 128,
        nullptr, nullptr, nullptr, zp);
    ks_nhwc_kernel<<<dim3(36, 8), 256, 0, stream>>>(ksmid_bf, w_ks2, b_ks2, ks);

    // ksp / sp  (ksp NHWC data-parallel from cat_x ch128..255)
    ksp_nhwc_kernel<<<dim3(36, 8), 256, 0, stream>>>(cat_x, w_sp1, ksp);
    sp_kernel<<<dim3(36, 8), 256, 0, stream>>>(ksp, w_sp, spb);

    // spatial_after + channel_after in one launch -> catfb
    spatchan_kernel<<<dim3(224, 8), 256, 0, stream>>>(xd, ks, spb, cat_x, kc, catfb);

    // r1 = conv3x3(catfb, w_fb)+b -> cat_r1 (bf16 NHWC; ksmid dead)
    mfma_conv<256, 9, false, 3><<<dim3(768), 512, 162304, stream>>>(
        catfb, nullptr, wfb_bf, b_fb, nullptr, 0, 0, cat_r1, 256, 256,
        nullptr, nullptr, nullptr, zp);

    // out = prelu(bn(conv3x3([cat_x | cat_r1], w_fuse)))
    mfma_conv<512, 9, true, 3><<<dim3(768), 512, 162304, stream>>>(
        cat_x, cat_r1, wfuse_bf, nullptr, out, 256L * HWl, 0, nullptr, 0, 256,
        bn2_g, bn2_b, prelu, zp);
}

// Round 19
// 611.541 us; speedup vs baseline: 1.0092x; 1.0092x over previous
//
#include <hip/hip_runtime.h>
#include <hip/hip_bf16.h>
#include <math.h>

#define HW 9216
#define IMG 96

typedef __bf16 bf16x8 __attribute__((ext_vector_type(8)));
typedef float  f32x4  __attribute__((ext_vector_type(4)));

__device__ __forceinline__ void gload16(const void* g, void* l) {
    __builtin_amdgcn_global_load_lds((const unsigned int*)g, (unsigned int*)l, 16, 0, 0);
}

#define WAITVN(N) asm volatile("s_waitcnt vmcnt(" #N ")" ::: "memory")
#define BARX()    { asm volatile("" ::: "memory"); __builtin_amdgcn_s_barrier(); asm volatile("" ::: "memory"); }

// ---------------------------------------------------------------------------
// BOTH NCHW fp32 -> NHWC bf16 transposes in one launch.
// grid (144, 20, 8): by<16 -> x (512ch, stride 512); by>=16 -> y2 (128ch).
// ---------------------------------------------------------------------------
__global__ __launch_bounds__(256) void nchw2nhwc2_kernel(
    const float* __restrict__ xsrc, const float* __restrict__ y2src,
    __hip_bfloat16* __restrict__ xdst, __hip_bfloat16* __restrict__ y2dst)
{
    __shared__ float tile[32][65];
    const int px0 = blockIdx.x * 64;
    const int by  = blockIdx.y;
    const int n   = blockIdx.z;
    const float* src; __hip_bfloat16* dst; long nss; int dstride, c0;
    if (by < 16) { src = xsrc;  dst = xdst;  nss = 512L * HW; dstride = 512; c0 = by * 32; }
    else         { src = y2src; dst = y2dst; nss = 256L * HW; dstride = 128; c0 = (by - 16) * 32; }
    const int tid = threadIdx.x;
    const int tx = tid & 63, ty = tid >> 6;
    #pragma unroll
    for (int i = 0; i < 8; ++i)
        tile[ty + i * 4][tx] = src[n * nss + (long)(c0 + ty + i * 4) * HW + px0 + tx];
    __syncthreads();
    const int ci = tid & 31, pxl = tid >> 5;
    #pragma unroll
    for (int j = 0; j < 8; ++j) {
        int px = pxl + j * 8;
        dst[((long)n * HW + px0 + px) * dstride + c0 + ci] = __float2bfloat16(tile[ci][px]);
    }
}

// ---------------------------------------------------------------------------
// all four weight conversions in ONE launch: dst[t][co][ci] = bf16(src[co][ci][t])
// ---------------------------------------------------------------------------
__global__ __launch_bounds__(256) void wconv_all_kernel(
    const float* __restrict__ w_down, const float* __restrict__ w_ks1,
    const float* __restrict__ w_fb,   const float* __restrict__ w_fuse,
    __hip_bfloat16* __restrict__ d_down, __hip_bfloat16* __restrict__ d_ks1,
    __hip_bfloat16* __restrict__ d_fb,   __hip_bfloat16* __restrict__ d_fuse)
{
    const float* src; __hip_bfloat16* dst; int cout, cin, taps;
    switch (blockIdx.y) {
        case 0:  src = w_down; dst = d_down; cout = 256; cin = 512; taps = 1; break;
        case 1:  src = w_ks1;  dst = d_ks1;  cout = 128; cin = 128; taps = 9; break;
        case 2:  src = w_fb;   dst = d_fb;   cout = 256; cin = 256; taps = 9; break;
        default: src = w_fuse; dst = d_fuse; cout = 256; cin = 512; taps = 9; break;
    }
    int idx = blockIdx.x * 256 + threadIdx.x;
    if (idx >= cout * cin) return;
    int co = idx / cin, ci = idx % cin;
    for (int t = 0; t < taps; ++t)
        dst[((long)t * cout + co) * cin + ci] = __float2bfloat16(src[(long)idx * taps + t]);
}

// ---------------------------------------------------------------------------
// MFMA implicit-GEMM conv (TAPS=9: 3x3 pad=1; TAPS=1: 1x1), bf16 in, fp32 acc.
// R17-proven form (VGPR 56): R10 geometry + B-address folding + counted
// per-wave vmcnt + T1 XCD swizzle. Staging uses stage(bb, adv) with
// `if (inval[t]) ptr += adv` (compiler hoists the select; R18's dual step
// arrays cost +16 VGPR and regressed — reverted).
// NCHW output only for co >= nchw_co0. SPLIT: dAB = (B - A) - 448 at ch 7->8.
// ---------------------------------------------------------------------------
template<int CIN, int TAPS, bool SPLIT, int NYL2>
__global__ __launch_bounds__(512, 1) void mfma_conv(
    const __hip_bfloat16* __restrict__ in_a,
    const __hip_bfloat16* __restrict__ in_b,
    const __hip_bfloat16* __restrict__ w_t,
    const float* __restrict__ bias,
    float* __restrict__ out_nchw, long nchw_nstride, int nchw_co0,
    __hip_bfloat16* __restrict__ out_nhwc, int nhwc_stride,
    int cout,
    const float* __restrict__ bng, const float* __restrict__ bnb,
    const float* __restrict__ pra,
    const __hip_bfloat16* __restrict__ zeropage)
{
    constexpr int ROWS = (TAPS == 9) ? 10 : 8;      // staged rows
    constexpr int COLS = (TAPS == 9) ? 98 : 96;
    constexpr int HOFF = (TAPS == 9) ? 1 : 0;
    constexpr int PSTR = SPLIT ? 256 : CIN;
    constexpr int NSEG_IN = ROWS * COLS * 4;        // 3920 / 3072
    constexpr int NSEG_W  = TAPS * 32 * 4;          // 1152 / 128
    constexpr int IN_BYTES = NSEG_IN * 16;          // 62720 / 49152
    constexpr int BUF = IN_BYTES + NSEG_W * 16;     // 81152 / 51200
    constexpr int NCHUNK = CIN / 32;
    constexpr int FULL_IN = NSEG_IN / 512;          // 7 / 6
    constexpr int IN_TAIL = NSEG_IN % 512;          // 336 / 0
    constexpr int FULL_W  = NSEG_W / 512;           // 2 / 0
    constexpr int W_TAIL  = NSEG_W % 512;           // 128 / 128
    constexpr int IT_IN = FULL_IN + (IN_TAIL ? 1 : 0);
    constexpr int IT_W  = FULL_W + (W_TAIL ? 1 : 0);
    constexpr int GROUPS = (TAPS == 9) ? 3 : 1;
    constexpr int KXN    = (TAPS == 9) ? 3 : 1;

    extern __shared__ __align__(16) char lds[];     // 2*BUF

    // ---- XCD-aware decode of flat block id ----
    const int id  = blockIdx.x;
    const int yb  = (id >> 3) & ((1 << NYL2) - 1);
    const int xz  = (id & 7) + 8 * (id >> (3 + NYL2));
    const int h0  = (xz % 12) * 8;
    const int n   = xz / 12;
    const int cob = yb * 32;

    const int tid  = threadIdx.x;
    const int lane = tid & 63;
    const int wave = tid >> 6;
    const int l16  = lane & 15, lg = lane >> 4;

    const long dAB = SPLIT ? ((const char*)in_b - (const char*)in_a - 448) : 0;

    // ---- input staging pointers (advance 64B per ci-chunk) ----
    const char* inptr[IT_IN];
    int inval[IT_IN];
    #pragma unroll
    for (int t = 0; t < IT_IN; ++t) {
        int seg = tid + t * 512;
        int s2 = (seg < NSEG_IN) ? seg : 0;
        int pix = s2 >> 2, qp = s2 & 3;
        int r = pix / COLS, c = pix % COLS;
        int h = h0 + r - HOFF, w = c - HOFF;
        int q = qp ^ ((c >> 1) & 3);                 // inverse-swizzled source slot
        bool valid = (h >= 0 && h < IMG && w >= 0 && w < IMG);
        inptr[t] = valid
            ? (const char*)(in_a + ((long)n * HW + h * IMG + w) * PSTR + q * 8)
            : (const char*)zeropage;
        inval[t] = valid ? 1 : 0;
    }
    // ---- weight staging pointers ----
    const char* wptr[IT_W];
    #pragma unroll
    for (int t = 0; t < IT_W; ++t) {
        int seg = tid + t * 512;
        int s2 = (seg < NSEG_W) ? seg : 0;
        int tap = s2 >> 7, rem = s2 & 127;
        int co = rem >> 2, qp = rem & 3;
        int q = qp ^ ((co >> 1) & 3);
        wptr[t] = (const char*)(w_t + ((long)tap * cout + cob + co) * CIN + q * 8);
    }

    auto stage = [&](int bb, long adv) {
        char* ib = lds + bb * BUF;
        char* wb = ib + IN_BYTES;
        #pragma unroll
        for (int t = 0; t < FULL_IN; ++t) {
            gload16(inptr[t], ib + (tid + t * 512) * 16);
            if (inval[t]) inptr[t] += adv;
        }
        if (IN_TAIL) {
            if (tid < IN_TAIL) {
                gload16(inptr[IT_IN - 1], ib + (tid + FULL_IN * 512) * 16);
                if (inval[IT_IN - 1]) inptr[IT_IN - 1] += adv;
            }
        }
        #pragma unroll
        for (int t = 0; t < FULL_W; ++t) {
            gload16(wptr[t], wb + (tid + t * 512) * 16);
            wptr[t] += 64;
        }
        if (W_TAIL) {
            if (tid < W_TAIL) {
                gload16(wptr[IT_W - 1], wb + (tid + FULL_W * 512) * 16);
                wptr[IT_W - 1] += 64;
            }
        }
    };

    f32x4 acc[2][6];
    #pragma unroll
    for (int m = 0; m < 2; ++m)
        #pragma unroll
        for (int nf = 0; nf < 6; ++nf) acc[m][nf] = (f32x4){0.f, 0.f, 0.f, 0.f};

    const int qa = lg ^ ((l16 >> 1) & 3);
    const int a_off = l16 * 64 + qa * 16;

    stage(0, 64);
    WAITVN(0); BARX();

    for (int ch = 0; ch < NCHUNK; ++ch) {
        if (ch + 1 < NCHUNK) {
            long adv = (SPLIT && (ch + 1) == 7) ? dAB : 64;
            stage((ch + 1) & 1, adv);
            // per-wave MIN of loads just issued (conservative)
            if constexpr (TAPS == 9) {
                if (wave < 2) { WAITVN(11); } else if (wave < 5) { WAITVN(10); } else { WAITVN(9); }
            } else {
                if (wave < 2) { WAITVN(7); } else { WAITVN(6); }
            }
        } else {
            WAITVN(0);
        }
        BARX();

        const char* ib = lds + (ch & 1) * BUF;
        const char* wb = ib + IN_BYTES;
        __builtin_amdgcn_s_setprio(1);
        #pragma unroll
        for (int g = 0; g < GROUPS; ++g) {
            const char* rowb = ib + (wave + g) * (COLS * 64);
            #pragma unroll
            for (int kx = 0; kx < KXN; ++kx) {
                const int tap = g * 3 + kx;          // compile-time in unroll
                bf16x8 a0 = *(const bf16x8*)(wb + tap * 2048 + a_off);
                bf16x8 a1 = *(const bf16x8*)(wb + tap * 2048 + 1024 + a_off);
                const int c0 = l16 + kx;
                const int qb = lg ^ ((c0 >> 1) & 3); // invariant in nf
                const char* bbase = rowb + c0 * 64 + qb * 16;
                #pragma unroll
                for (int nf = 0; nf < 6; ++nf) {
                    bf16x8 b = *(const bf16x8*)(bbase + nf * 1024);
                    acc[0][nf] = __builtin_amdgcn_mfma_f32_16x16x32_bf16(a0, b, acc[0][nf], 0, 0, 0);
                    acc[1][nf] = __builtin_amdgcn_mfma_f32_16x16x32_bf16(a1, b, acc[1][nf], 0, 0, 0);
                }
            }
        }
        __builtin_amdgcn_s_setprio(0);
        BARX();
    }

    // ---- epilogue ----
    const int hrow = h0 + wave;
    #pragma unroll
    for (int m = 0; m < 2; ++m) {
        const int co = cob + m * 16 + lg * 4;
        float bs[4], g4[4], b4[4], p4[4];
        #pragma unroll
        for (int r = 0; r < 4; ++r) bs[r] = bias ? bias[co + r] : 0.f;
        if (bng) {
            #pragma unroll
            for (int r = 0; r < 4; ++r) { g4[r] = bng[co + r]; b4[r] = bnb[co + r]; p4[r] = pra[co + r]; }
        }
        #pragma unroll
        for (int nf = 0; nf < 6; ++nf) {
            const int wcol = nf * 16 + l16;
            const long px = (long)hrow * IMG + wcol;
            float v[4];
            #pragma unroll
            for (int r = 0; r < 4; ++r) {
                v[r] = acc[m][nf][r] + bs[r];
                if (bng) {
                    v[r] = v[r] * g4[r] + b4[r];
                    v[r] = (v[r] >= 0.f) ? v[r] : p4[r] * v[r];
                }
            }
            if (out_nchw && co >= nchw_co0) {
                #pragma unroll
                for (int r = 0; r < 4; ++r)
                    out_nchw[(long)n * nchw_nstride + (long)(co - nchw_co0 + r) * HW + px] = v[r];
            }
            if (out_nhwc) {
                union { __hip_bfloat16 h[4]; uint2 u; } pk;
                #pragma unroll
                for (int r = 0; r < 4; ++r) pk.h[r] = __float2bfloat16(v[r]);
                *reinterpret_cast<uint2*>(&out_nhwc[((long)n * HW + px) * nhwc_stride + co]) = pk.u;
            }
        }
    }
}

// ---------------------------------------------------------------------------
// BOTH pools in one launch. grid (137, 8): bx<9 -> x-pool bin bx (from cat_x
// NHWC ch0..127); bx>=9 -> y-pool channel bx-9 (fp32 NCHW).
// ---------------------------------------------------------------------------
__global__ __launch_bounds__(256) void pool_both_kernel(
    const __hip_bfloat16* __restrict__ catx, const float* __restrict__ y,
    float* __restrict__ gl, float* __restrict__ py)
{
    const int bx = blockIdx.x;
    const int n  = blockIdx.y;
    const int tid = threadIdx.x;
    __shared__ float red[16][16][8];
    if (bx < 9) {
        const int bin = bx;
        const int bh = bin / 3, bw = bin % 3;
        const int cg  = tid & 15;
        const int pxl = tid >> 4;
        const long pbase = (long)n * HW;
        float acc[8];
        #pragma unroll
        for (int j = 0; j < 8; ++j) acc[j] = 0.f;
        for (int it = 0; it < 64; ++it) {
            const int i = pxl + it * 16;
            const int h = bh * 32 + (i >> 5);
            const int w = bw * 32 + (i & 31);
            bf16x8 v = *reinterpret_cast<const bf16x8*>(&catx[(pbase + h * IMG + w) * 256 + cg * 8]);
            #pragma unroll
            for (int j = 0; j < 8; ++j) acc[j] += (float)v[j];
        }
        #pragma unroll
        for (int j = 0; j < 8; ++j) red[pxl][cg][j] = acc[j];
        __syncthreads();
        if (tid < 128) {
            const int cg2 = tid & 15, j = tid >> 4;
            float s = 0.f;
            #pragma unroll
            for (int p = 0; p < 16; ++p) s += red[p][cg2][j];
            gl[((long)n * 128 + cg2 * 8 + j) * 9 + bin] = s * (1.f / 1024.f);
        }
    } else {
        const int c = bx - 9;
        const float* src = y + ((long)n * 256 + c) * HW;
        float local[9];
        #pragma unroll
        for (int k = 0; k < 9; ++k) local[k] = 0.f;
        for (int i = tid; i < HW; i += 256) {
            int h = i / 96, w = i % 96;
            local[(h / 32) * 3 + (w / 32)] += src[i];
        }
        float* red2 = &red[0][0][0];   // reuse LDS: [9][4]
        const int wv = tid >> 6, lane = tid & 63;
        #pragma unroll
        for (int k = 0; k < 9; ++k) {
            float v = local[k];
            for (int off = 32; off > 0; off >>= 1) v += __shfl_down(v, off, 64);
            if (lane == 0) red2[k * 4 + wv] = v;
        }
        __syncthreads();
        if (tid < 9) {
            float s = (red2[tid * 4 + 0] + red2[tid * 4 + 1] + red2[tid * 4 + 2] + red2[tid * 4 + 3]) * (1.f / 1024.f);
            py[((long)n * 128 + c) * 9 + tid] = s;
        }
    }
}

// ---------------------------------------------------------------------------
__global__ __launch_bounds__(128) void attkc_kernel(
    const float* __restrict__ gl, const float* __restrict__ py,
    const float* __restrict__ w_ce, const float* __restrict__ w_gd,
    const float* __restrict__ bng, const float* __restrict__ bnb,
    const float* __restrict__ w_kc, const float* __restrict__ b_kc,
    float* __restrict__ kc)
{
    const int n = blockIdx.x, c = threadIdx.x;
    __shared__ float py_s[128][9];
    #pragma unroll
    for (int k = 0; k < 9; ++k) py_s[c][k] = py[((long)n * 128 + c) * 9 + k];
    __syncthreads();
    float g[9];
    #pragma unroll
    for (int k = 0; k < 9; ++k) g[k] = gl[((long)n * 128 + c) * 9 + k];
    float t[5];
    #pragma unroll
    for (int l = 0; l < 5; ++l) {
        float s = 0.f;
        #pragma unroll
        for (int k = 0; k < 9; ++k) s += g[k] * w_ce[l * 9 + k];
        s = s * bng[c] + bnb[c];
        t[l] = s > 0.f ? s : 0.f;
    }
    float att[9];
    #pragma unroll
    for (int k = 0; k < 9; ++k) {
        float s = 0.f;
        #pragma unroll
        for (int l = 0; l < 5; ++l) s += t[l] * w_gd[k * 5 + l];
        att[k] = 1.f / (1.f + expf(-s));
    }
    float kc0[9];
    float bk = b_kc[c];
    #pragma unroll
    for (int k = 0; k < 9; ++k) kc0[k] = bk;
    for (int c2 = 0; c2 < 128; ++c2) {
        float wv = w_kc[c * 128 + c2];
        #pragma unroll
        for (int k = 0; k < 9; ++k) kc0[k] += wv * py_s[c2][k];
    }
    #pragma unroll
    for (int k = 0; k < 9; ++k)
        kc[((long)n * 128 + c) * 9 + k] = kc0[k] * att[k];
}

// ---------------------------------------------------------------------------
// ks (1x1 conv 128->9 on ksmid_bf NHWC) + ksp (3x3 conv x2 -> 1ch) in ONE
// launch: grid (36, 8, 2); z=0 -> ks, z=1 -> ksp.
// ---------------------------------------------------------------------------
__global__ __launch_bounds__(256) void ks_ksp_kernel(
    const __hip_bfloat16* __restrict__ ksmid, const float* __restrict__ w_ks2,
    const float* __restrict__ b_ks2, float* __restrict__ ks,
    const __hip_bfloat16* __restrict__ catx, const float* __restrict__ w_sp1,
    float* __restrict__ ksp)
{
    const int tid = threadIdx.x;
    const int p = blockIdx.x * 256 + tid;
    const int n = blockIdx.y;
    if (blockIdx.z == 0) {
        __shared__ float w_s[9 * 128];
        for (int i = tid; i < 1152; i += 256) w_s[i] = w_ks2[i];
        __syncthreads();
        const __hip_bfloat16* row = ksmid + ((long)n * HW + p) * 128;
        float acc[9];
        #pragma unroll
        for (int k = 0; k < 9; ++k) acc[k] = b_ks2[k];
        #pragma unroll
        for (int vq = 0; vq < 16; ++vq) {
            bf16x8 v = *reinterpret_cast<const bf16x8*>(&row[vq * 8]);
            #pragma unroll
            for (int j = 0; j < 8; ++j) {
                float f = (float)v[j];
                #pragma unroll
                for (int k = 0; k < 9; ++k) acc[k] += w_s[k * 128 + vq * 8 + j] * f;
            }
        }
        #pragma unroll
        for (int k = 0; k < 9; ++k) ks[((long)n * 9 + k) * HW + p] = acc[k];
    } else {
        __shared__ float w_s2[9][128];
        for (int i = tid; i < 1152; i += 256) {
            int ci = i / 9, tap = i % 9;            // src layout [ci][tap]
            w_s2[tap][ci] = w_sp1[i];
        }
        __syncthreads();
        const int h = p / 96, w = p % 96;
        const long pbase = (long)n * HW;
        float acc = 0.f;
        #pragma unroll
        for (int ky = 0; ky < 3; ++ky) {
            const int hh = h + ky - 1;
            if (hh < 0 || hh >= IMG) continue;
            #pragma unroll
            for (int kx = 0; kx < 3; ++kx) {
                const int ww = w + kx - 1;
                if (ww < 0 || ww >= IMG) continue;
                const int tap = ky * 3 + kx;
                const __hip_bfloat16* row = &catx[(pbase + hh * IMG + ww) * 256 + 128];
                #pragma unroll
                for (int vq = 0; vq < 16; ++vq) {
                    bf16x8 v = *reinterpret_cast<const bf16x8*>(&row[vq * 8]);
                    #pragma unroll
                    for (int j = 0; j < 8; ++j)
                        acc += w_s2[tap][vq * 8 + j] * (float)v[j];
                }
            }
        }
        ksp[pbase + p] = acc;
    }
}

// ---------------------------------------------------------------------------
__global__ __launch_bounds__(256) void sp_kernel(
    const float* __restrict__ ksp, const float* __restrict__ w_sp,
    float* __restrict__ sp)
{
    const int p = blockIdx.x * 256 + threadIdx.x;
    const int n = blockIdx.y;
    const int h = p / 96, w = p % 96;
    const float* kp = ksp + (long)n * HW;
    float acc = 0.f;
    #pragma unroll
    for (int dy = 0; dy < 3; ++dy)
        #pragma unroll
        for (int dx = 0; dx < 3; ++dx) {
            int hh = h + dy - 1, ww = w + dx - 1;
            if (hh < 0 || hh >= 96 || ww < 0 || ww >= 96) continue;
            float s = 0.f, m = -1e30f;
            #pragma unroll
            for (int iy = 0; iy < 3; ++iy)
                #pragma unroll
                for (int ix = 0; ix < 3; ++ix) {
                    int h2 = hh + iy - 1, w2 = ww + ix - 1;
                    float v = (h2 >= 0 && h2 < 96 && w2 >= 0 && w2 < 96) ? kp[h2 * 96 + w2] : 0.f;
                    s += v; m = fmaxf(m, v);
                }
            acc += w_sp[dy * 3 + dx] * (s * (1.f / 9.f)) + w_sp[9 + dy * 3 + dx] * m;
        }
    sp[(long)n * HW + p] = 1.f / (1.f + expf(-acc));
}

// ---------------------------------------------------------------------------
// spatial_after + channel_after in one launch. grid (224, 8):
// bx<96 -> channel row h=bx (catfb ch0..127); bx>=96 -> spatial cc=bx-96
// (catfb ch128..255, raw-reshape gather cc = p/72). xd = x2 only.
// ---------------------------------------------------------------------------
__global__ __launch_bounds__(256) void spatchan_kernel(
    const float* __restrict__ xd, const float* __restrict__ ks,
    const float* __restrict__ sp, const __hip_bfloat16* __restrict__ catx,
    const float* __restrict__ kc, __hip_bfloat16* __restrict__ catfb)
{
    const int bx = blockIdx.x;
    const int n  = blockIdx.y;
    const int tid = threadIdx.x;
    __shared__ float plane[HW];
    if (bx < 96) {
        // ---- channel_after ----
        const int h  = bx;
        const int cg = (tid & 15) * 8;
        const int w0 = tid >> 4;
        float k9[8][9];
        #pragma unroll
        for (int j = 0; j < 8; ++j)
            #pragma unroll
            for (int t = 0; t < 9; ++t) k9[j][t] = kc[((long)n * 128 + cg + j) * 9 + t];
        const long pbase = (long)n * HW;
        for (int it = 0; it < 6; ++it) {
            const int w = w0 + it * 16;
            float acc[8];
            #pragma unroll
            for (int j = 0; j < 8; ++j) acc[j] = 0.f;
            #pragma unroll
            for (int ky = 0; ky < 3; ++ky) {
                const int hh = h + ky - 1;
                if (hh < 0 || hh >= IMG) continue;
                #pragma unroll
                for (int kx = 0; kx < 3; ++kx) {
                    const int ww = w + kx - 1;
                    if (ww < 0 || ww >= IMG) continue;
                    bf16x8 v = *reinterpret_cast<const bf16x8*>(
                        &catx[(pbase + hh * IMG + ww) * 256 + cg]);
                    #pragma unroll
                    for (int j = 0; j < 8; ++j)
                        acc[j] += k9[j][ky * 3 + kx] * (float)v[j];
                }
            }
            union { __hip_bfloat16 hh[8]; uint4 u; } pk;
            #pragma unroll
            for (int j = 0; j < 8; ++j) pk.hh[j] = __float2bfloat16(acc[j]);
            *reinterpret_cast<uint4*>(&catfb[(pbase + h * IMG + w) * 256 + cg]) = pk.u;
        }
    } else {
        // ---- spatial_after ----
        const int cc = bx - 96;
        const float* src = xd + ((long)n * 128 + cc) * HW;
        for (int i = tid; i < HW / 4; i += 256)
            *reinterpret_cast<float4*>(&plane[i * 4]) = *reinterpret_cast<const float4*>(&src[i * 4]);
        __syncthreads();
        const int c  = tid & 127;
        const int pr = tid >> 7;
        const int c9 = c * 9;
        for (int j = 0; j < 36; ++j) {
            const int pl = pr + j * 2;
            const int p  = cc * 72 + pl;
            float spv = sp[(long)n * HW + p];
            float kv[9];
            #pragma unroll
            for (int k = 0; k < 9; ++k) kv[k] = ks[((long)n * 9 + k) * HW + p] * spv;
            const int base = pl * 1152 + c9;
            int kk0 = base / 9216;
            int r20 = base - kk0 * 9216;
            int h20 = r20 / 96;
            int w20 = r20 - h20 * 96;
            float acc = 0.f;
            #pragma unroll
            for (int k = 0; k < 9; ++k) {
                int kk = kk0, h2 = h20, w2 = w20 + k;
                if (w2 >= 96) { h2 += 1; w2 -= 96; }
                if (h2 >= 96) { kk += 1; h2 -= 96; }
                int hh = h2 + kk / 3 - 1;
                int ww = w2 + kk % 3 - 1;
                float v = (hh >= 0 && hh < 96 && ww >= 0 && ww < 96) ? plane[hh * 96 + ww] : 0.f;
                acc += v * kv[k];
            }
            catfb[((long)n * HW + p) * 256 + 128 + c] = __float2bfloat16(acc);
        }
    }
}

// ---------------------------------------------------------------------------
extern "C" void kernel_launch(void* const* d_in, const int* in_sizes, int n_in,
                              void* d_out, int out_size, void* d_ws, size_t ws_size,
                              hipStream_t stream)
{
    const float* x      = (const float*)d_in[0];
    const float* y      = (const float*)d_in[1];
    const float* w_down = (const float*)d_in[2];
    const float* b_down = (const float*)d_in[3];
    const float* w_ce   = (const float*)d_in[4];
    const float* w_gd   = (const float*)d_in[5];
    const float* bn_g   = (const float*)d_in[6];
    const float* bn_b   = (const float*)d_in[7];
    const float* w_kc   = (const float*)d_in[8];
    const float* b_kc   = (const float*)d_in[9];
    const float* w_ks1  = (const float*)d_in[10];
    const float* b_ks1  = (const float*)d_in[11];
    const float* w_ks2  = (const float*)d_in[12];
    const float* b_ks2  = (const float*)d_in[13];
    const float* w_sp1  = (const float*)d_in[14];
    const float* w_sp   = (const float*)d_in[15];
    const float* w_fb   = (const float*)d_in[16];
    const float* b_fb   = (const float*)d_in[17];
    const float* w_fuse = (const float*)d_in[18];
    const float* bn2_g  = (const float*)d_in[19];
    const float* bn2_b  = (const float*)d_in[20];
    const float* prelu  = (const float*)d_in[21];
    float* out = (float*)d_out;
    char* ws = (char*)d_ws;

    const long HWl = HW;
    // --- workspace layout ---
    float* xd = (float*)ws;                               ws += 8L * 128 * HWl * 4;  // 37.7MB (x2 only)
    char* region2 = ws;                                   ws += 8L * HWl * 512 * 2;  // 75.5MB
    __hip_bfloat16* x_t      = (__hip_bfloat16*)region2;          // [N][HW][512] bf16
    __hip_bfloat16* cat_r1   = (__hip_bfloat16*)region2;          // [N][HW][256] bf16
    __hip_bfloat16* ksmid_bf = (__hip_bfloat16*)region2;          // [N][HW][128] bf16
    __hip_bfloat16* catfb    = (__hip_bfloat16*)(region2 + 8L * HWl * 256 * 2); // [N][HW][256]
    __hip_bfloat16* cat_x  = (__hip_bfloat16*)ws;         ws += 8L * HWl * 256 * 2;  // 37.7MB
    __hip_bfloat16* y2t    = (__hip_bfloat16*)ws;         ws += 8L * HWl * 128 * 2;  // 18.9MB
    __hip_bfloat16* wdown_bf = (__hip_bfloat16*)ws;       ws += 1L * 256 * 512 * 2;
    __hip_bfloat16* wks1_bf  = (__hip_bfloat16*)ws;       ws += 9L * 128 * 128 * 2;
    __hip_bfloat16* wfb_bf   = (__hip_bfloat16*)ws;       ws += 9L * 256 * 256 * 2;
    __hip_bfloat16* wfuse_bf = (__hip_bfloat16*)ws;       ws += 9L * 256 * 512 * 2;
    float* ks   = (float*)ws;  ws += 8L * 9 * HWl * 4;
    float* ksp  = (float*)ws;  ws += 8L * HWl * 4;
    float* spb  = (float*)ws;  ws += 8L * HWl * 4;
    float* gl   = (float*)ws;  ws += 8L * 128 * 9 * 4;
    float* py   = (float*)ws;  ws += 8L * 128 * 9 * 4;
    float* kc   = (float*)ws;  ws += 8L * 128 * 9 * 4;
    __hip_bfloat16* zp = (__hip_bfloat16*)ws;  ws += 256;

    (void)hipMemsetAsync((void*)zp, 0, 256, stream);

    // all weight conversions in one launch
    wconv_all_kernel<<<dim3(512, 4), 256, 0, stream>>>(
        w_down, w_ks1, w_fb, w_fuse, wdown_bf, wks1_bf, wfb_bf, wfuse_bf);

    // x AND y2 -> NHWC bf16 in one launch
    nchw2nhwc2_kernel<<<dim3(144, 20, 8), 256, 0, stream>>>(
        x, y + 128L * HWl, x_t, y2t);

    // 1x1 down conv -> xd (x2 only, fp32) + cat_x (bf16 NHWC)
    mfma_conv<512, 1, false, 3><<<dim3(768), 512, 102400, stream>>>(
        x_t, nullptr, wdown_bf, b_down, xd, 128L * HWl, 128, cat_x, 256, 256,
        nullptr, nullptr, nullptr, zp);

    // pools (both) / attention
    pool_both_kernel<<<dim3(137, 8), 256, 0, stream>>>(cat_x, y, gl, py);
    attkc_kernel<<<dim3(8), 128, 0, stream>>>(gl, py, w_ce, w_gd, bn_g, bn_b, w_kc, b_kc, kc);

    // ks_mid = conv3x3(y2) -> ksmid_bf (bf16 NHWC; x_t dead now)
    mfma_conv<128, 9, false, 2><<<dim3(384), 512, 162304, stream>>>(
        y2t, nullptr, wks1_bf, b_ks1, nullptr, 0, 0, ksmid_bf, 128, 128,
        nullptr, nullptr, nullptr, zp);

    // ks + ksp in one launch
    ks_ksp_kernel<<<dim3(36, 8, 2), 256, 0, stream>>>(
        ksmid_bf, w_ks2, b_ks2, ks, cat_x, w_sp1, ksp);
    sp_kernel<<<dim3(36, 8), 256, 0, stream>>>(ksp, w_sp, spb);

    // spatial_after + channel_after in one launch -> catfb
    spatchan_kernel<<<dim3(224, 8), 256, 0, stream>>>(xd, ks, spb, cat_x, kc, catfb);

    // r1 = conv3x3(catfb, w_fb)+b -> cat_r1 (bf16 NHWC; ksmid dead)
    mfma_conv<256, 9, false, 3><<<dim3(768), 512, 162304, stream>>>(
        catfb, nullptr, wfb_bf, b_fb, nullptr, 0, 0, cat_r1, 256, 256,
        nullptr, nullptr, nullptr, zp);

    // out = prelu(bn(conv3x3([cat_x | cat_r1], w_fuse)))
    mfma_conv<512, 9, true, 3><<<dim3(768), 512, 162304, stream>>>(
        cat_x, cat_r1, wfuse_bf, nullptr, out, 256L * HWl, 0, nullptr, 0, 256,
        bn2_g, bn2_b, prelu, zp);
}

// Round 20
// 607.034 us; speedup vs baseline: 1.0167x; 1.0074x over previous
//
#include <hip/hip_runtime.h>
#include <hip/hip_bf16.h>
#include <math.h>

#define HW 9216
#define IMG 96

typedef __bf16 bf16x8 __attribute__((ext_vector_type(8)));
typedef float  f32x4  __attribute__((ext_vector_type(4)));

__device__ __forceinline__ void gload16(const void* g, void* l) {
    __builtin_amdgcn_global_load_lds((const unsigned int*)g, (unsigned int*)l, 16, 0, 0);
}

#define WAITVN(N) asm volatile("s_waitcnt vmcnt(" #N ")" ::: "memory")
#define BARX()    { asm volatile("" ::: "memory"); __builtin_amdgcn_s_barrier(); asm volatile("" ::: "memory"); }

// ---------------------------------------------------------------------------
// BOTH NCHW fp32 -> NHWC bf16 transposes in one launch.
// grid (144, 20, 8): by<16 -> x (512ch, stride 512); by>=16 -> y2 (128ch).
// ---------------------------------------------------------------------------
__global__ __launch_bounds__(256) void nchw2nhwc2_kernel(
    const float* __restrict__ xsrc, const float* __restrict__ y2src,
    __hip_bfloat16* __restrict__ xdst, __hip_bfloat16* __restrict__ y2dst)
{
    __shared__ float tile[32][65];
    const int px0 = blockIdx.x * 64;
    const int by  = blockIdx.y;
    const int n   = blockIdx.z;
    const float* src; __hip_bfloat16* dst; long nss; int dstride, c0;
    if (by < 16) { src = xsrc;  dst = xdst;  nss = 512L * HW; dstride = 512; c0 = by * 32; }
    else         { src = y2src; dst = y2dst; nss = 256L * HW; dstride = 128; c0 = (by - 16) * 32; }
    const int tid = threadIdx.x;
    const int tx = tid & 63, ty = tid >> 6;
    #pragma unroll
    for (int i = 0; i < 8; ++i)
        tile[ty + i * 4][tx] = src[n * nss + (long)(c0 + ty + i * 4) * HW + px0 + tx];
    __syncthreads();
    const int ci = tid & 31, pxl = tid >> 5;
    #pragma unroll
    for (int j = 0; j < 8; ++j) {
        int px = pxl + j * 8;
        dst[((long)n * HW + px0 + px) * dstride + c0 + ci] = __float2bfloat16(tile[ci][px]);
    }
}

// ---------------------------------------------------------------------------
// all four weight conversions in ONE launch: dst[t][co][ci] = bf16(src[co][ci][t])
// ---------------------------------------------------------------------------
__global__ __launch_bounds__(256) void wconv_all_kernel(
    const float* __restrict__ w_down, const float* __restrict__ w_ks1,
    const float* __restrict__ w_fb,   const float* __restrict__ w_fuse,
    __hip_bfloat16* __restrict__ d_down, __hip_bfloat16* __restrict__ d_ks1,
    __hip_bfloat16* __restrict__ d_fb,   __hip_bfloat16* __restrict__ d_fuse)
{
    const float* src; __hip_bfloat16* dst; int cout, cin, taps;
    switch (blockIdx.y) {
        case 0:  src = w_down; dst = d_down; cout = 256; cin = 512; taps = 1; break;
        case 1:  src = w_ks1;  dst = d_ks1;  cout = 128; cin = 128; taps = 9; break;
        case 2:  src = w_fb;   dst = d_fb;   cout = 256; cin = 256; taps = 9; break;
        default: src = w_fuse; dst = d_fuse; cout = 256; cin = 512; taps = 9; break;
    }
    int idx = blockIdx.x * 256 + threadIdx.x;
    if (idx >= cout * cin) return;
    int co = idx / cin, ci = idx % cin;
    for (int t = 0; t < taps; ++t)
        dst[((long)t * cout + co) * cin + ci] = __float2bfloat16(src[(long)idx * taps + t]);
}

// ---------------------------------------------------------------------------
// MFMA implicit-GEMM conv (TAPS=9: 3x3 pad=1; TAPS=1: 1x1), bf16 in, fp32 acc.
// R17-proven form (VGPR 56): R10 geometry + B-address folding + counted
// per-wave vmcnt + T1 XCD swizzle. R20: s_setprio REMOVED — T5 is
// null-to-negative on barrier-synced lockstep schedules (catalog m190);
// our 8 waves are lockstep, so the wrap was at best dead weight.
// NCHW output only for co >= nchw_co0. SPLIT: dAB = (B - A) - 448 at ch 7->8.
// ---------------------------------------------------------------------------
template<int CIN, int TAPS, bool SPLIT, int NYL2>
__global__ __launch_bounds__(512, 1) void mfma_conv(
    const __hip_bfloat16* __restrict__ in_a,
    const __hip_bfloat16* __restrict__ in_b,
    const __hip_bfloat16* __restrict__ w_t,
    const float* __restrict__ bias,
    float* __restrict__ out_nchw, long nchw_nstride, int nchw_co0,
    __hip_bfloat16* __restrict__ out_nhwc, int nhwc_stride,
    int cout,
    const float* __restrict__ bng, const float* __restrict__ bnb,
    const float* __restrict__ pra,
    const __hip_bfloat16* __restrict__ zeropage)
{
    constexpr int ROWS = (TAPS == 9) ? 10 : 8;      // staged rows
    constexpr int COLS = (TAPS == 9) ? 98 : 96;
    constexpr int HOFF = (TAPS == 9) ? 1 : 0;
    constexpr int PSTR = SPLIT ? 256 : CIN;
    constexpr int NSEG_IN = ROWS * COLS * 4;        // 3920 / 3072
    constexpr int NSEG_W  = TAPS * 32 * 4;          // 1152 / 128
    constexpr int IN_BYTES = NSEG_IN * 16;          // 62720 / 49152
    constexpr int BUF = IN_BYTES + NSEG_W * 16;     // 81152 / 51200
    constexpr int NCHUNK = CIN / 32;
    constexpr int FULL_IN = NSEG_IN / 512;          // 7 / 6
    constexpr int IN_TAIL = NSEG_IN % 512;          // 336 / 0
    constexpr int FULL_W  = NSEG_W / 512;           // 2 / 0
    constexpr int W_TAIL  = NSEG_W % 512;           // 128 / 128
    constexpr int IT_IN = FULL_IN + (IN_TAIL ? 1 : 0);
    constexpr int IT_W  = FULL_W + (W_TAIL ? 1 : 0);
    constexpr int GROUPS = (TAPS == 9) ? 3 : 1;
    constexpr int KXN    = (TAPS == 9) ? 3 : 1;

    extern __shared__ __align__(16) char lds[];     // 2*BUF

    // ---- XCD-aware decode of flat block id ----
    const int id  = blockIdx.x;
    const int yb  = (id >> 3) & ((1 << NYL2) - 1);
    const int xz  = (id & 7) + 8 * (id >> (3 + NYL2));
    const int h0  = (xz % 12) * 8;
    const int n   = xz / 12;
    const int cob = yb * 32;

    const int tid  = threadIdx.x;
    const int lane = tid & 63;
    const int wave = tid >> 6;
    const int l16  = lane & 15, lg = lane >> 4;

    const long dAB = SPLIT ? ((const char*)in_b - (const char*)in_a - 448) : 0;

    // ---- input staging pointers (advance 64B per ci-chunk) ----
    const char* inptr[IT_IN];
    int inval[IT_IN];
    #pragma unroll
    for (int t = 0; t < IT_IN; ++t) {
        int seg = tid + t * 512;
        int s2 = (seg < NSEG_IN) ? seg : 0;
        int pix = s2 >> 2, qp = s2 & 3;
        int r = pix / COLS, c = pix % COLS;
        int h = h0 + r - HOFF, w = c - HOFF;
        int q = qp ^ ((c >> 1) & 3);                 // inverse-swizzled source slot
        bool valid = (h >= 0 && h < IMG && w >= 0 && w < IMG);
        inptr[t] = valid
            ? (const char*)(in_a + ((long)n * HW + h * IMG + w) * PSTR + q * 8)
            : (const char*)zeropage;
        inval[t] = valid ? 1 : 0;
    }
    // ---- weight staging pointers ----
    const char* wptr[IT_W];
    #pragma unroll
    for (int t = 0; t < IT_W; ++t) {
        int seg = tid + t * 512;
        int s2 = (seg < NSEG_W) ? seg : 0;
        int tap = s2 >> 7, rem = s2 & 127;
        int co = rem >> 2, qp = rem & 3;
        int q = qp ^ ((co >> 1) & 3);
        wptr[t] = (const char*)(w_t + ((long)tap * cout + cob + co) * CIN + q * 8);
    }

    auto stage = [&](int bb, long adv) {
        char* ib = lds + bb * BUF;
        char* wb = ib + IN_BYTES;
        #pragma unroll
        for (int t = 0; t < FULL_IN; ++t) {
            gload16(inptr[t], ib + (tid + t * 512) * 16);
            if (inval[t]) inptr[t] += adv;
        }
        if (IN_TAIL) {
            if (tid < IN_TAIL) {
                gload16(inptr[IT_IN - 1], ib + (tid + FULL_IN * 512) * 16);
                if (inval[IT_IN - 1]) inptr[IT_IN - 1] += adv;
            }
        }
        #pragma unroll
        for (int t = 0; t < FULL_W; ++t) {
            gload16(wptr[t], wb + (tid + t * 512) * 16);
            wptr[t] += 64;
        }
        if (W_TAIL) {
            if (tid < W_TAIL) {
                gload16(wptr[IT_W - 1], wb + (tid + FULL_W * 512) * 16);
                wptr[IT_W - 1] += 64;
            }
        }
    };

    f32x4 acc[2][6];
    #pragma unroll
    for (int m = 0; m < 2; ++m)
        #pragma unroll
        for (int nf = 0; nf < 6; ++nf) acc[m][nf] = (f32x4){0.f, 0.f, 0.f, 0.f};

    const int qa = lg ^ ((l16 >> 1) & 3);
    const int a_off = l16 * 64 + qa * 16;

    stage(0, 64);
    WAITVN(0); BARX();

    for (int ch = 0; ch < NCHUNK; ++ch) {
        if (ch + 1 < NCHUNK) {
            long adv = (SPLIT && (ch + 1) == 7) ? dAB : 64;
            stage((ch + 1) & 1, adv);
            // per-wave MIN of loads just issued (conservative)
            if constexpr (TAPS == 9) {
                if (wave < 2) { WAITVN(11); } else if (wave < 5) { WAITVN(10); } else { WAITVN(9); }
            } else {
                if (wave < 2) { WAITVN(7); } else { WAITVN(6); }
            }
        } else {
            WAITVN(0);
        }
        BARX();

        const char* ib = lds + (ch & 1) * BUF;
        const char* wb = ib + IN_BYTES;
        #pragma unroll
        for (int g = 0; g < GROUPS; ++g) {
            const char* rowb = ib + (wave + g) * (COLS * 64);
            #pragma unroll
            for (int kx = 0; kx < KXN; ++kx) {
                const int tap = g * 3 + kx;          // compile-time in unroll
                bf16x8 a0 = *(const bf16x8*)(wb + tap * 2048 + a_off);
                bf16x8 a1 = *(const bf16x8*)(wb + tap * 2048 + 1024 + a_off);
                const int c0 = l16 + kx;
                const int qb = lg ^ ((c0 >> 1) & 3); // invariant in nf
                const char* bbase = rowb + c0 * 64 + qb * 16;
                #pragma unroll
                for (int nf = 0; nf < 6; ++nf) {
                    bf16x8 b = *(const bf16x8*)(bbase + nf * 1024);
                    acc[0][nf] = __builtin_amdgcn_mfma_f32_16x16x32_bf16(a0, b, acc[0][nf], 0, 0, 0);
                    acc[1][nf] = __builtin_amdgcn_mfma_f32_16x16x32_bf16(a1, b, acc[1][nf], 0, 0, 0);
                }
            }
        }
        BARX();
    }

    // ---- epilogue ----
    const int hrow = h0 + wave;
    #pragma unroll
    for (int m = 0; m < 2; ++m) {
        const int co = cob + m * 16 + lg * 4;
        float bs[4], g4[4], b4[4], p4[4];
        #pragma unroll
        for (int r = 0; r < 4; ++r) bs[r] = bias ? bias[co + r] : 0.f;
        if (bng) {
            #pragma unroll
            for (int r = 0; r < 4; ++r) { g4[r] = bng[co + r]; b4[r] = bnb[co + r]; p4[r] = pra[co + r]; }
        }
        #pragma unroll
        for (int nf = 0; nf < 6; ++nf) {
            const int wcol = nf * 16 + l16;
            const long px = (long)hrow * IMG + wcol;
            float v[4];
            #pragma unroll
            for (int r = 0; r < 4; ++r) {
                v[r] = acc[m][nf][r] + bs[r];
                if (bng) {
                    v[r] = v[r] * g4[r] + b4[r];
                    v[r] = (v[r] >= 0.f) ? v[r] : p4[r] * v[r];
                }
            }
            if (out_nchw && co >= nchw_co0) {
                #pragma unroll
                for (int r = 0; r < 4; ++r)
                    out_nchw[(long)n * nchw_nstride + (long)(co - nchw_co0 + r) * HW + px] = v[r];
            }
            if (out_nhwc) {
                union { __hip_bfloat16 h[4]; uint2 u; } pk;
                #pragma unroll
                for (int r = 0; r < 4; ++r) pk.h[r] = __float2bfloat16(v[r]);
                *reinterpret_cast<uint2*>(&out_nhwc[((long)n * HW + px) * nhwc_stride + co]) = pk.u;
            }
        }
    }
}

// ---------------------------------------------------------------------------
// BOTH pools in one launch. grid (137, 8): bx<9 -> x-pool bin bx (from cat_x
// NHWC ch0..127); bx>=9 -> y-pool channel bx-9 (fp32 NCHW).
// ---------------------------------------------------------------------------
__global__ __launch_bounds__(256) void pool_both_kernel(
    const __hip_bfloat16* __restrict__ catx, const float* __restrict__ y,
    float* __restrict__ gl, float* __restrict__ py)
{
    const int bx = blockIdx.x;
    const int n  = blockIdx.y;
    const int tid = threadIdx.x;
    __shared__ float red[16][16][8];
    if (bx < 9) {
        const int bin = bx;
        const int bh = bin / 3, bw = bin % 3;
        const int cg  = tid & 15;
        const int pxl = tid >> 4;
        const long pbase = (long)n * HW;
        float acc[8];
        #pragma unroll
        for (int j = 0; j < 8; ++j) acc[j] = 0.f;
        for (int it = 0; it < 64; ++it) {
            const int i = pxl + it * 16;
            const int h = bh * 32 + (i >> 5);
            const int w = bw * 32 + (i & 31);
            bf16x8 v = *reinterpret_cast<const bf16x8*>(&catx[(pbase + h * IMG + w) * 256 + cg * 8]);
            #pragma unroll
            for (int j = 0; j < 8; ++j) acc[j] += (float)v[j];
        }
        #pragma unroll
        for (int j = 0; j < 8; ++j) red[pxl][cg][j] = acc[j];
        __syncthreads();
        if (tid < 128) {
            const int cg2 = tid & 15, j = tid >> 4;
            float s = 0.f;
            #pragma unroll
            for (int p = 0; p < 16; ++p) s += red[p][cg2][j];
            gl[((long)n * 128 + cg2 * 8 + j) * 9 + bin] = s * (1.f / 1024.f);
        }
    } else {
        const int c = bx - 9;
        const float* src = y + ((long)n * 256 + c) * HW;
        float local[9];
        #pragma unroll
        for (int k = 0; k < 9; ++k) local[k] = 0.f;
        for (int i = tid; i < HW; i += 256) {
            int h = i / 96, w = i % 96;
            local[(h / 32) * 3 + (w / 32)] += src[i];
        }
        float* red2 = &red[0][0][0];   // reuse LDS: [9][4]
        const int wv = tid >> 6, lane = tid & 63;
        #pragma unroll
        for (int k = 0; k < 9; ++k) {
            float v = local[k];
            for (int off = 32; off > 0; off >>= 1) v += __shfl_down(v, off, 64);
            if (lane == 0) red2[k * 4 + wv] = v;
        }
        __syncthreads();
        if (tid < 9) {
            float s = (red2[tid * 4 + 0] + red2[tid * 4 + 1] + red2[tid * 4 + 2] + red2[tid * 4 + 3]) * (1.f / 1024.f);
            py[((long)n * 128 + c) * 9 + tid] = s;
        }
    }
}

// ---------------------------------------------------------------------------
__global__ __launch_bounds__(128) void attkc_kernel(
    const float* __restrict__ gl, const float* __restrict__ py,
    const float* __restrict__ w_ce, const float* __restrict__ w_gd,
    const float* __restrict__ bng, const float* __restrict__ bnb,
    const float* __restrict__ w_kc, const float* __restrict__ b_kc,
    float* __restrict__ kc)
{
    const int n = blockIdx.x, c = threadIdx.x;
    __shared__ float py_s[128][9];
    #pragma unroll
    for (int k = 0; k < 9; ++k) py_s[c][k] = py[((long)n * 128 + c) * 9 + k];
    __syncthreads();
    float g[9];
    #pragma unroll
    for (int k = 0; k < 9; ++k) g[k] = gl[((long)n * 128 + c) * 9 + k];
    float t[5];
    #pragma unroll
    for (int l = 0; l < 5; ++l) {
        float s = 0.f;
        #pragma unroll
        for (int k = 0; k < 9; ++k) s += g[k] * w_ce[l * 9 + k];
        s = s * bng[c] + bnb[c];
        t[l] = s > 0.f ? s : 0.f;
    }
    float att[9];
    #pragma unroll
    for (int k = 0; k < 9; ++k) {
        float s = 0.f;
        #pragma unroll
        for (int l = 0; l < 5; ++l) s += t[l] * w_gd[k * 5 + l];
        att[k] = 1.f / (1.f + expf(-s));
    }
    float kc0[9];
    float bk = b_kc[c];
    #pragma unroll
    for (int k = 0; k < 9; ++k) kc0[k] = bk;
    for (int c2 = 0; c2 < 128; ++c2) {
        float wv = w_kc[c * 128 + c2];
        #pragma unroll
        for (int k = 0; k < 9; ++k) kc0[k] += wv * py_s[c2][k];
    }
    #pragma unroll
    for (int k = 0; k < 9; ++k)
        kc[((long)n * 128 + c) * 9 + k] = kc0[k] * att[k];
}

// ---------------------------------------------------------------------------
// ks (1x1 conv 128->9 on ksmid_bf NHWC) + ksp (3x3 conv x2 -> 1ch) in ONE
// launch: grid (36, 8, 2); z=0 -> ks, z=1 -> ksp.
// ---------------------------------------------------------------------------
__global__ __launch_bounds__(256) void ks_ksp_kernel(
    const __hip_bfloat16* __restrict__ ksmid, const float* __restrict__ w_ks2,
    const float* __restrict__ b_ks2, float* __restrict__ ks,
    const __hip_bfloat16* __restrict__ catx, const float* __restrict__ w_sp1,
    float* __restrict__ ksp)
{
    const int tid = threadIdx.x;
    const int p = blockIdx.x * 256 + tid;
    const int n = blockIdx.y;
    if (blockIdx.z == 0) {
        __shared__ float w_s[9 * 128];
        for (int i = tid; i < 1152; i += 256) w_s[i] = w_ks2[i];
        __syncthreads();
        const __hip_bfloat16* row = ksmid + ((long)n * HW + p) * 128;
        float acc[9];
        #pragma unroll
        for (int k = 0; k < 9; ++k) acc[k] = b_ks2[k];
        #pragma unroll
        for (int vq = 0; vq < 16; ++vq) {
            bf16x8 v = *reinterpret_cast<const bf16x8*>(&row[vq * 8]);
            #pragma unroll
            for (int j = 0; j < 8; ++j) {
                float f = (float)v[j];
                #pragma unroll
                for (int k = 0; k < 9; ++k) acc[k] += w_s[k * 128 + vq * 8 + j] * f;
            }
        }
        #pragma unroll
        for (int k = 0; k < 9; ++k) ks[((long)n * 9 + k) * HW + p] = acc[k];
    } else {
        __shared__ float w_s2[9][128];
        for (int i = tid; i < 1152; i += 256) {
            int ci = i / 9, tap = i % 9;            // src layout [ci][tap]
            w_s2[tap][ci] = w_sp1[i];
        }
        __syncthreads();
        const int h = p / 96, w = p % 96;
        const long pbase = (long)n * HW;
        float acc = 0.f;
        #pragma unroll
        for (int ky = 0; ky < 3; ++ky) {
            const int hh = h + ky - 1;
            if (hh < 0 || hh >= IMG) continue;
            #pragma unroll
            for (int kx = 0; kx < 3; ++kx) {
                const int ww = w + kx - 1;
                if (ww < 0 || ww >= IMG) continue;
                const int tap = ky * 3 + kx;
                const __hip_bfloat16* row = &catx[(pbase + hh * IMG + ww) * 256 + 128];
                #pragma unroll
                for (int vq = 0; vq < 16; ++vq) {
                    bf16x8 v = *reinterpret_cast<const bf16x8*>(&row[vq * 8]);
                    #pragma unroll
                    for (int j = 0; j < 8; ++j)
                        acc += w_s2[tap][vq * 8 + j] * (float)v[j];
                }
            }
        }
        ksp[pbase + p] = acc;
    }
}

// ---------------------------------------------------------------------------
__global__ __launch_bounds__(256) void sp_kernel(
    const float* __restrict__ ksp, const float* __restrict__ w_sp,
    float* __restrict__ sp)
{
    const int p = blockIdx.x * 256 + threadIdx.x;
    const int n = blockIdx.y;
    const int h = p / 96, w = p % 96;
    const float* kp = ksp + (long)n * HW;
    float acc = 0.f;
    #pragma unroll
    for (int dy = 0; dy < 3; ++dy)
        #pragma unroll
        for (int dx = 0; dx < 3; ++dx) {
            int hh = h + dy - 1, ww = w + dx - 1;
            if (hh < 0 || hh >= 96 || ww < 0 || ww >= 96) continue;
            float s = 0.f, m = -1e30f;
            #pragma unroll
            for (int iy = 0; iy < 3; ++iy)
                #pragma unroll
                for (int ix = 0; ix < 3; ++ix) {
                    int h2 = hh + iy - 1, w2 = ww + ix - 1;
                    float v = (h2 >= 0 && h2 < 96 && w2 >= 0 && w2 < 96) ? kp[h2 * 96 + w2] : 0.f;
                    s += v; m = fmaxf(m, v);
                }
            acc += w_sp[dy * 3 + dx] * (s * (1.f / 9.f)) + w_sp[9 + dy * 3 + dx] * m;
        }
    sp[(long)n * HW + p] = 1.f / (1.f + expf(-acc));
}

// ---------------------------------------------------------------------------
// spatial_after + channel_after in one launch. grid (224, 8):
// bx<96 -> channel row h=bx (catfb ch0..127); bx>=96 -> spatial cc=bx-96
// (catfb ch128..255, raw-reshape gather cc = p/72). xd = x2 only.
// ---------------------------------------------------------------------------
__global__ __launch_bounds__(256) void spatchan_kernel(
    const float* __restrict__ xd, const float* __restrict__ ks,
    const float* __restrict__ sp, const __hip_bfloat16* __restrict__ catx,
    const float* __restrict__ kc, __hip_bfloat16* __restrict__ catfb)
{
    const int bx = blockIdx.x;
    const int n  = blockIdx.y;
    const int tid = threadIdx.x;
    __shared__ float plane[HW];
    if (bx < 96) {
        // ---- channel_after ----
        const int h  = bx;
        const int cg = (tid & 15) * 8;
        const int w0 = tid >> 4;
        float k9[8][9];
        #pragma unroll
        for (int j = 0; j < 8; ++j)
            #pragma unroll
            for (int t = 0; t < 9; ++t) k9[j][t] = kc[((long)n * 128 + cg + j) * 9 + t];
        const long pbase = (long)n * HW;
        for (int it = 0; it < 6; ++it) {
            const int w = w0 + it * 16;
            float acc[8];
            #pragma unroll
            for (int j = 0; j < 8; ++j) acc[j] = 0.f;
            #pragma unroll
            for (int ky = 0; ky < 3; ++ky) {
                const int hh = h + ky - 1;
                if (hh < 0 || hh >= IMG) continue;
                #pragma unroll
                for (int kx = 0; kx < 3; ++kx) {
                    const int ww = w + kx - 1;
                    if (ww < 0 || ww >= IMG) continue;
                    bf16x8 v = *reinterpret_cast<const bf16x8*>(
                        &catx[(pbase + hh * IMG + ww) * 256 + cg]);
                    #pragma unroll
                    for (int j = 0; j < 8; ++j)
                        acc[j] += k9[j][ky * 3 + kx] * (float)v[j];
                }
            }
            union { __hip_bfloat16 hh[8]; uint4 u; } pk;
            #pragma unroll
            for (int j = 0; j < 8; ++j) pk.hh[j] = __float2bfloat16(acc[j]);
            *reinterpret_cast<uint4*>(&catfb[(pbase + h * IMG + w) * 256 + cg]) = pk.u;
        }
    } else {
        // ---- spatial_after ----
        const int cc = bx - 96;
        const float* src = xd + ((long)n * 128 + cc) * HW;
        for (int i = tid; i < HW / 4; i += 256)
            *reinterpret_cast<float4*>(&plane[i * 4]) = *reinterpret_cast<const float4*>(&src[i * 4]);
        __syncthreads();
        const int c  = tid & 127;
        const int pr = tid >> 7;
        const int c9 = c * 9;
        for (int j = 0; j < 36; ++j) {
            const int pl = pr + j * 2;
            const int p  = cc * 72 + pl;
            float spv = sp[(long)n * HW + p];
            float kv[9];
            #pragma unroll
            for (int k = 0; k < 9; ++k) kv[k] = ks[((long)n * 9 + k) * HW + p] * spv;
            const int base = pl * 1152 + c9;
            int kk0 = base / 9216;
            int r20 = base - kk0 * 9216;
            int h20 = r20 / 96;
            int w20 = r20 - h20 * 96;
            float acc = 0.f;
            #pragma unroll
            for (int k = 0; k < 9; ++k) {
                int kk = kk0, h2 = h20, w2 = w20 + k;
                if (w2 >= 96) { h2 += 1; w2 -= 96; }
                if (h2 >= 96) { kk += 1; h2 -= 96; }
                int hh = h2 + kk / 3 - 1;
                int ww = w2 + kk % 3 - 1;
                float v = (hh >= 0 && hh < 96 && ww >= 0 && ww < 96) ? plane[hh * 96 + ww] : 0.f;
                acc += v * kv[k];
            }
            catfb[((long)n * HW + p) * 256 + 128 + c] = __float2bfloat16(acc);
        }
    }
}

// ---------------------------------------------------------------------------
extern "C" void kernel_launch(void* const* d_in, const int* in_sizes, int n_in,
                              void* d_out, int out_size, void* d_ws, size_t ws_size,
                              hipStream_t stream)
{
    const float* x      = (const float*)d_in[0];
    const float* y      = (const float*)d_in[1];
    const float* w_down = (const float*)d_in[2];
    const float* b_down = (const float*)d_in[3];
    const float* w_ce   = (const float*)d_in[4];
    const float* w_gd   = (const float*)d_in[5];
    const float* bn_g   = (const float*)d_in[6];
    const float* bn_b   = (const float*)d_in[7];
    const float* w_kc   = (const float*)d_in[8];
    const float* b_kc   = (const float*)d_in[9];
    const float* w_ks1  = (const float*)d_in[10];
    const float* b_ks1  = (const float*)d_in[11];
    const float* w_ks2  = (const float*)d_in[12];
    const float* b_ks2  = (const float*)d_in[13];
    const float* w_sp1  = (const float*)d_in[14];
    const float* w_sp   = (const float*)d_in[15];
    const float* w_fb   = (const float*)d_in[16];
    const float* b_fb   = (const float*)d_in[17];
    const float* w_fuse = (const float*)d_in[18];
    const float* bn2_g  = (const float*)d_in[19];
    const float* bn2_b  = (const float*)d_in[20];
    const float* prelu  = (const float*)d_in[21];
    float* out = (float*)d_out;
    char* ws = (char*)d_ws;

    const long HWl = HW;
    // --- workspace layout ---
    float* xd = (float*)ws;                               ws += 8L * 128 * HWl * 4;  // 37.7MB (x2 only)
    char* region2 = ws;                                   ws += 8L * HWl * 512 * 2;  // 75.5MB
    __hip_bfloat16* x_t      = (__hip_bfloat16*)region2;          // [N][HW][512] bf16
    __hip_bfloat16* cat_r1   = (__hip_bfloat16*)region2;          // [N][HW][256] bf16
    __hip_bfloat16* ksmid_bf = (__hip_bfloat16*)region2;          // [N][HW][128] bf16
    __hip_bfloat16* catfb    = (__hip_bfloat16*)(region2 + 8L * HWl * 256 * 2); // [N][HW][256]
    __hip_bfloat16* cat_x  = (__hip_bfloat16*)ws;         ws += 8L * HWl * 256 * 2;  // 37.7MB
    __hip_bfloat16* y2t    = (__hip_bfloat16*)ws;         ws += 8L * HWl * 128 * 2;  // 18.9MB
    __hip_bfloat16* wdown_bf = (__hip_bfloat16*)ws;       ws += 1L * 256 * 512 * 2;
    __hip_bfloat16* wks1_bf  = (__hip_bfloat16*)ws;       ws += 9L * 128 * 128 * 2;
    __hip_bfloat16* wfb_bf   = (__hip_bfloat16*)ws;       ws += 9L * 256 * 256 * 2;
    __hip_bfloat16* wfuse_bf = (__hip_bfloat16*)ws;       ws += 9L * 256 * 512 * 2;
    float* ks   = (float*)ws;  ws += 8L * 9 * HWl * 4;
    float* ksp  = (float*)ws;  ws += 8L * HWl * 4;
    float* spb  = (float*)ws;  ws += 8L * HWl * 4;
    float* gl   = (float*)ws;  ws += 8L * 128 * 9 * 4;
    float* py   = (float*)ws;  ws += 8L * 128 * 9 * 4;
    float* kc   = (float*)ws;  ws += 8L * 128 * 9 * 4;
    __hip_bfloat16* zp = (__hip_bfloat16*)ws;  ws += 256;

    (void)hipMemsetAsync((void*)zp, 0, 256, stream);

    // all weight conversions in one launch
    wconv_all_kernel<<<dim3(512, 4), 256, 0, stream>>>(
        w_down, w_ks1, w_fb, w_fuse, wdown_bf, wks1_bf, wfb_bf, wfuse_bf);

    // x AND y2 -> NHWC bf16 in one launch
    nchw2nhwc2_kernel<<<dim3(144, 20, 8), 256, 0, stream>>>(
        x, y + 128L * HWl, x_t, y2t);

    // 1x1 down conv -> xd (x2 only, fp32) + cat_x (bf16 NHWC)
    mfma_conv<512, 1, false, 3><<<dim3(768), 512, 102400, stream>>>(
        x_t, nullptr, wdown_bf, b_down, xd, 128L * HWl, 128, cat_x, 256, 256,
        nullptr, nullptr, nullptr, zp);

    // pools (both) / attention
    pool_both_kernel<<<dim3(137, 8), 256, 0, stream>>>(cat_x, y, gl, py);
    attkc_kernel<<<dim3(8), 128, 0, stream>>>(gl, py, w_ce, w_gd, bn_g, bn_b, w_kc, b_kc, kc);

    // ks_mid = conv3x3(y2) -> ksmid_bf (bf16 NHWC; x_t dead now)
    mfma_conv<128, 9, false, 2><<<dim3(384), 512, 162304, stream>>>(
        y2t, nullptr, wks1_bf, b_ks1, nullptr, 0, 0, ksmid_bf, 128, 128,
        nullptr, nullptr, nullptr, zp);

    // ks + ksp in one launch
    ks_ksp_kernel<<<dim3(36, 8, 2), 256, 0, stream>>>(
        ksmid_bf, w_ks2, b_ks2, ks, cat_x, w_sp1, ksp);
    sp_kernel<<<dim3(36, 8), 256, 0, stream>>>(ksp, w_sp, spb);

    // spatial_after + channel_after in one launch -> catfb
    spatchan_kernel<<<dim3(224, 8), 256, 0, stream>>>(xd, ks, spb, cat_x, kc, catfb);

    // r1 = conv3x3(catfb, w_fb)+b -> cat_r1 (bf16 NHWC; ksmid dead)
    mfma_conv<256, 9, false, 3><<<dim3(768), 512, 162304, stream>>>(
        catfb, nullptr, wfb_bf, b_fb, nullptr, 0, 0, cat_r1, 256, 256,
        nullptr, nullptr, nullptr, zp);

    // out = prelu(bn(conv3x3([cat_x | cat_r1], w_fuse)))
    mfma_conv<512, 9, true, 3><<<dim3(768), 512, 162304, stream>>>(
        cat_x, cat_r1, wfuse_bf, nullptr, out, 256L * HWl, 0, nullptr, 0, 256,
        bn2_g, bn2_b, prelu, zp);
}